// Round 23
// baseline (40.854 us; speedup 1.0000x reference)
//
#include <hip/hip_runtime.h>

#define TT 16384
#define DD 2048
#define EE 64

typedef __attribute__((ext_vector_type(8))) short bf16x8;
typedef __attribute__((ext_vector_type(8))) unsigned short ushort8;
typedef __attribute__((ext_vector_type(4))) float f32x4;

__device__ __forceinline__ unsigned short bf16_rne(float f) {
    unsigned u = __float_as_uint(f);
    return (unsigned short)((u + 0x7FFFu + ((u >> 16) & 1u)) >> 16);
}
__device__ __forceinline__ float bf16_f32(unsigned short h) {
    return __uint_as_float(((unsigned)h) << 16);
}
__device__ __forceinline__ unsigned cvt_pk(float lo, float hi) {
    unsigned r;
    asm("v_cvt_pk_bf16_f32 %0, %1, %2" : "=v"(r) : "v"(lo), "v"(hi));
    return r;
}
__device__ __forceinline__ bf16x8 pack4(unsigned a, unsigned b, unsigned c, unsigned d) {
    union { unsigned u[4]; bf16x8 v; } t;
    t.u[0] = a; t.u[1] = b; t.u[2] = c; t.u[3] = d;
    return t.v;
}
__device__ __forceinline__ void gload16(void* lds, const void* g) {
    __builtin_amdgcn_global_load_lds(
        (const __attribute__((address_space(1))) unsigned int*)g,
        (__attribute__((address_space(3))) unsigned int*)lds, 16, 0, 0);
}
#define SB0() __builtin_amdgcn_sched_barrier(0)

// ---------------------------------------------------------------------------
// W [2048][64] f32 -> wpack (R5/R13-verified 16x16x32 A-frag layout).
// wpack[K0][h][m][lane][j] = bf16 hi/lo of wg[(K0*32+(lane>>4)*8+j)*64 + m*16+(lane&15)]
__global__ __launch_bounds__(256)
void wconv(const float* __restrict__ wg, unsigned short* __restrict__ wpack) {
    const int t = (int)blockIdx.x * 256 + threadIdx.x;  // 32768 threads
    const int K0 = t >> 9, h = (t >> 8) & 1, m = (t >> 6) & 3, lane = t & 63;
    const int e = m * 16 + (lane & 15);
    const int ks = K0 * 32 + (lane >> 4) * 8;
    ushort8 v;
#pragma unroll
    for (int j = 0; j < 8; ++j) {
        const float f = wg[(size_t)(ks + j) * EE + e];
        const unsigned short hi = bf16_rne(f);
        v[j] = h ? bf16_rne(f - bf16_f32(hi)) : hi;
    }
    *(ushort8*)(wpack + ((size_t)(K0 * 8 + h * 4 + m) * 64 + lane) * 8) = v;
}

// ---------------------------------------------------------------------------
// W SHARED VIA LDS: block = 512 thr = 8 waves (q = K-quarter 0..3, tg =
// token-group 0..1), 64 tokens/block.  Waves (q,0) and (q,1) consume the
// SAME W chunk -> staged ONCE per block into a 2-slot LDS ring (tg0 stages
// hi-frags, tg1 lo-frags; 4 KB each) => W L2 traffic 256->128 MB vs R19,
// while keeping R19's 32-tok/wave MFMA, depth-3 x rings, 128-B segments,
// 8 waves/CU.  2 barriers/step (slot-ready / reads-done); counted vmcnt(12)
// drains exactly {x(s), W(s)} so the 3-deep pipe survives the barriers.
// Grid 256 = 1 block/CU.  LDS 160 KB (96 x-rings + 64 W ring; bins/overlay
// overlaid into x arena post-loop).
__global__ __launch_bounds__(512, 1)
void gate_fused(const float* __restrict__ x, const unsigned short* __restrict__ wpack,
                const float* __restrict__ loads, float* __restrict__ out,
                float* __restrict__ binpart) {
    __shared__ __align__(16) float arena[24576];  // 96 KB: 8 waves x 3 x 1024 f
    __shared__ __align__(16) float wlds[16384];   // 64 KB: 2 slots x 32 KB

    const int tid = threadIdx.x, lane = tid & 63, w = tid >> 6;
    const int q = w >> 1, tg = w & 1;
    const int tb = (int)blockIdx.x;

    f32x4 a0[4] = {{0,0,0,0},{0,0,0,0},{0,0,0,0},{0,0,0,0}};  // tok tg*32+0..15
    f32x4 a1[4] = {{0,0,0,0},{0,0,0,0},{0,0,0,0},{0,0,0,0}};  // tok tg*32+16..31

    float* ring = arena + (size_t)w * 3072;
    float *sp0 = ring, *sp1 = ring + 1024, *sp2 = ring + 2048;

    // stage x step s (this wave's 32 rows x 32 k = 4 KB): 4 x gload16,
    // 8 rows x 128 B each, source-side chunk swizzle (R19 verbatim + tg base).
    auto stage_x = [&](int s, float* sb) {
#pragma unroll
        for (int i = 0; i < 4; ++i) {
            const int rowp = lane >> 3;
            const int c = (lane & 7) ^ rowp;
            gload16(sb + i * 256,
                    x + (size_t)(tb * 64 + tg * 32 + i * 8 + rowp) * DD
                      + q * 512 + s * 32 + c * 4);
        }
    };
    // stage this wave's half of W chunk (q, s) into W slot: 4 x gload16.
    // tg0 -> hi frags 0..3, tg1 -> lo frags 4..7.  1 KB/frag, linear dest.
    auto stage_W = [&](int s, int slot) {
        const unsigned short* srcb =
            wpack + (size_t)(q * 16 + s) * 4096 + (size_t)(tg * 4) * 512 + lane * 8;
        float* db = wlds + (size_t)slot * 8192 + q * 2048 + tg * 4 * 256;
#pragma unroll
        for (int j = 0; j < 4; ++j)
            gload16(db + j * 256, srcb + (size_t)j * 512);
    };
    // read this q's 8 W frags from the LDS slot (contiguous 16 B/lane b128).
    auto readW = [&](int slot, bf16x8 (&wh)[4], bf16x8 (&wl)[4]) {
        const unsigned short* b = (const unsigned short*)wlds
            + (size_t)slot * 16384 + q * 4096 + lane * 8;
#pragma unroll
        for (int m = 0; m < 4; ++m) {
            wh[m] = *(const bf16x8*)(b + (size_t)m * 512);
            wl[m] = *(const bf16x8*)(b + (size_t)(4 + m) * 512);
        }
    };
    // both tiles' B-frags (R19 verbatim; sw identical for r and 16+r).
    auto readx = [&](const float* sb, f32x4& va0, f32x4& vb0, f32x4& va1, f32x4& vb1) {
        const int rl = lane & 15;
        const int kgc = (lane >> 4) << 1;
        const int sw = rl & 7;
        va0 = *(const f32x4*)(sb + rl * 32 + ((kgc) ^ sw) * 4);
        vb0 = *(const f32x4*)(sb + rl * 32 + ((kgc + 1) ^ sw) * 4);
        va1 = *(const f32x4*)(sb + (16 + rl) * 32 + ((kgc) ^ sw) * 4);
        vb1 = *(const f32x4*)(sb + (16 + rl) * 32 + ((kgc + 1) ^ sw) * 4);
    };
    auto domfma = [&](const f32x4& va, const f32x4& vb,
                      bf16x8 (&wh)[4], bf16x8 (&wl)[4], f32x4 (&ac)[4]) {
        const float cf[8] = {va.x, va.y, va.z, va.w, vb.x, vb.y, vb.z, vb.w};
        unsigned ph[4], pl[4];
#pragma unroll
        for (int j = 0; j < 4; ++j) {
            ph[j] = cvt_pk(cf[2 * j], cf[2 * j + 1]);
            const float h0 = __uint_as_float(ph[j] << 16);
            const float h1 = __uint_as_float(ph[j] & 0xFFFF0000u);
            pl[j] = cvt_pk(cf[2 * j] - h0, cf[2 * j + 1] - h1);
        }
        const bf16x8 bhi = pack4(ph[0], ph[1], ph[2], ph[3]);
        const bf16x8 blo = pack4(pl[0], pl[1], pl[2], pl[3]);
#pragma unroll
        for (int m = 0; m < 4; ++m) {
            ac[m] = __builtin_amdgcn_mfma_f32_16x16x32_bf16(wh[m], bhi, ac[m], 0, 0, 0);
            ac[m] = __builtin_amdgcn_mfma_f32_16x16x32_bf16(wh[m], blo, ac[m], 0, 0, 0);
            ac[m] = __builtin_amdgcn_mfma_f32_16x16x32_bf16(wl[m], bhi, ac[m], 0, 0, 0);
        }
    };

    // prologue FIFO (per wave): W0(4) x0(4) W1(4) x1(4) x2(4) = 20.
    stage_W(0, 0); SB0();
    stage_x(0, sp0); SB0();
    stage_W(1, 1); SB0();
    stage_x(1, sp1); SB0();
    stage_x(2, sp2); SB0();

    // ITER(s): vmcnt(VM) drains own {x(s), W(s)}; bar1 -> slot readable by
    // all; ds_read x+W; lgkm0; bar2 -> all reads done (WAR safe); issue
    // W(s+2)->slot s&1 and x(s+3)->slot s%3; MFMA.
#define ITER(s, XS, WS, VM, DOW, DOS)                                     \
    do {                                                                  \
        asm volatile("s_waitcnt vmcnt(" #VM ")" ::: "memory"); SB0();     \
        __builtin_amdgcn_s_barrier(); SB0();                              \
        f32x4 va0, vb0, va1, vb1;                                         \
        bf16x8 wh[4], wl[4];                                              \
        readx(sp##XS, va0, vb0, va1, vb1);                                \
        readW(WS, wh, wl); SB0();                                         \
        asm volatile("s_waitcnt lgkmcnt(0)" ::: "memory"); SB0();         \
        __builtin_amdgcn_s_barrier(); SB0();                              \
        if (DOW) stage_W((s) + 2, ((s) + 2) & 1);                         \
        SB0();                                                            \
        if (DOS) stage_x((s) + 3, sp##XS);                                \
        SB0();                                                            \
        domfma(va0, vb0, wh, wl, a0);                                     \
        domfma(va1, vb1, wh, wl, a1);                                     \
    } while (0)

    ITER(0, 0, 0, 12, 1, 1);  ITER(1, 1, 1, 12, 1, 1);
    ITER(2, 2, 0, 12, 1, 1);  ITER(3, 0, 1, 12, 1, 1);
    ITER(4, 1, 0, 12, 1, 1);  ITER(5, 2, 1, 12, 1, 1);
    ITER(6, 0, 0, 12, 1, 1);  ITER(7, 1, 1, 12, 1, 1);
    ITER(8, 2, 0, 12, 1, 1);  ITER(9, 0, 1, 12, 1, 1);
    ITER(10, 1, 0, 12, 1, 1); ITER(11, 2, 1, 12, 1, 1);
    ITER(12, 0, 0, 12, 1, 1);   // issues W14, x15
    ITER(13, 1, 1, 12, 1, 0);   // issues W15
    ITER(14, 2, 0, 8, 0, 0);    // drains x14+W14
    ITER(15, 0, 1, 0, 0, 0);    // drains x15+W15
#undef ITER

    // ---- epilogue: overlay reduce + top-2 + bins (all waves stay alive) --
    float* binsp = arena;                 // [64] overlaid
    float* ovbase = arena + 64;           // 6 x 2304 floats overlaid
    __syncthreads();                      // K-loop reads done everywhere
    if (q != 0) {
        float* p = ovbase + (size_t)((q - 1) * 2 + tg) * 2304 + lane * 36;
#pragma unroll
        for (int m = 0; m < 4; ++m) {
            *(f32x4*)(p + m * 4) = a0[m];
            *(f32x4*)(p + 16 + m * 4) = a1[m];
        }
    }
    if (w == 0) binsp[lane] = 0.0f;
    __syncthreads();

    if (q == 0) {
#pragma unroll 1
        for (int qq = 0; qq < 3; ++qq) {
            const float* p = ovbase + (size_t)(qq * 2 + tg) * 2304 + lane * 36;
#pragma unroll
            for (int m = 0; m < 4; ++m) {
                const f32x4 t0 = *(const f32x4*)(p + m * 4);
                const f32x4 t1 = *(const f32x4*)(p + 16 + m * 4);
                a0[m].x += t0.x; a0[m].y += t0.y; a0[m].z += t0.z; a0[m].w += t0.w;
                a1[m].x += t1.x; a1[m].y += t1.y; a1[m].z += t1.z; a1[m].w += t1.w;
            }
        }
        const int col = lane & 15;
        const int erow = (lane >> 4) * 4;
        auto topk = [&](f32x4 (&r)[4], int tokbase) {
            float v1 = -3.4e38f, u1 = 0.0f, v2 = -3.4e38f, u2 = 0.0f;
            int i1 = 0x7fffffff, i2 = 0x7fffffff;
#pragma unroll
            for (int m = 0; m < 4; ++m)
#pragma unroll
                for (int rr = 0; rr < 4; ++rr) {
                    const int e = m * 16 + erow + rr;
                    const float u = r[m][rr];
                    const float b = u - (loads[e] - 0.015625f) * 2.0f;
                    if ((b > v1) || (b == v1 && e < i1)) {
                        v2 = v1; u2 = u1; i2 = i1;
                        v1 = b;  u1 = u;  i1 = e;
                    } else if ((b > v2) || (b == v2 && e < i2)) {
                        v2 = b; u2 = u; i2 = e;
                    }
                }
#pragma unroll
            for (int s = 0; s < 2; ++s) {
                const int mask = 16 << s;
                const float ov1 = __shfl_xor(v1, mask), ou1 = __shfl_xor(u1, mask);
                const float ov2 = __shfl_xor(v2, mask), ou2 = __shfl_xor(u2, mask);
                const int oi1 = __shfl_xor(i1, mask), oi2 = __shfl_xor(i2, mask);
                if ((ov1 > v1) || (ov1 == v1 && oi1 < i1)) {
                    if ((v1 > ov2) || (v1 == ov2 && i1 < oi2)) { v2 = v1; u2 = u1; i2 = i1; }
                    else                                        { v2 = ov2; u2 = ou2; i2 = oi2; }
                    v1 = ov1; u1 = ou1; i1 = oi1;
                } else if ((ov1 > v2) || (ov1 == v2 && oi1 < i2)) {
                    v2 = ov1; u2 = ou1; i2 = oi1;
                }
            }
            if (lane < 16) {
                const int tok = tokbase + col;
                const float mx = fmaxf(u1, u2);
                const float e1 = __expf(u1 - mx), e2 = __expf(u2 - mx);
                const float w1 = e1 / (e1 + e2), w2 = e2 / (e1 + e2);
                *(float2*)(out + 2 * tok) = make_float2(w1, w2);
                *(float2*)(out + 2 * TT + 2 * tok) = make_float2((float)i1, (float)i2);
                atomicAdd(&binsp[i1], w1);
                atomicAdd(&binsp[i2], w2);
            }
        };
        topk(a0, tb * 64 + tg * 32);
        topk(a1, tb * 64 + tg * 32 + 16);
    }
    __syncthreads();
    if (w == 0) binpart[(size_t)tb * 64 + lane] = binsp[lane];
}

// ---------------------------------------------------------------------------
// Merged finalize: 1 block x 1024 thr sums [256][64] rows (fixed order) + EMA.
__global__ __launch_bounds__(1024)
void finalize(const float* __restrict__ binpart, const float* __restrict__ loads,
              float* __restrict__ out) {
    __shared__ float p[16][64];
    const int e = threadIdx.x & 63, sub = threadIdx.x >> 6;  // 0..15
    float s = 0.0f;
#pragma unroll
    for (int r = 0; r < 16; ++r)
        s += binpart[(size_t)(sub * 16 + r) * 64 + e];
    p[sub][e] = s;
    __syncthreads();
    if (sub == 0) {
        float tot = 0.0f;
#pragma unroll
        for (int k = 0; k < 16; ++k) tot += p[k][e];
        out[4 * TT + e] = 0.9f * loads[e] + 0.1f * (tot * (1.0f / 16384.0f));
    }
}

// ---------------------------------------------------------------------------
extern "C" void kernel_launch(void* const* d_in, const int* in_sizes, int n_in,
                              void* d_out, int out_size, void* d_ws, size_t ws_size,
                              hipStream_t stream) {
    const float* x = (const float*)d_in[0];      // [16384, 2048]
    const float* wg = (const float*)d_in[1];     // [2048, 64]
    const float* loads = (const float*)d_in[2];  // [64]
    float* out = (float*)d_out;

    unsigned short* wpack = (unsigned short*)d_ws;               // 512 KB
    float* binpart = (float*)(wpack + (size_t)64 * 8 * 64 * 8);  // [256][64]

    hipLaunchKernelGGL(wconv, dim3(128), dim3(256), 0, stream, wg, wpack);
    hipLaunchKernelGGL(gate_fused, dim3(256), dim3(512), 0, stream,
                       x, wpack, loads, out, binpart);
    hipLaunchKernelGGL(finalize, dim3(1), dim3(1024), 0, stream,
                       binpart, loads, out);
}